// Round 1
// 736.690 us; speedup vs baseline: 1.0840x; 1.0840x over previous
//
#include <hip/hip_runtime.h>
#include <math.h>

// pGNN on MI355X. N=100000, E=1.6M, IN=256, HID=64, OUT=40. MU=0.1, P=2.5, K=2.
// Round 9: mlp1 rewritten on the matrix pipe. mfma_f32_16x16x32_bf16 with
// split-precision (x=xh+xl, W=wh+wl bf16; acc = xh*wh + xh*wl + xl*wh in f32)
// => ~fp32 accuracy (missing xl*wl ~ 2^-18 rel). 64 rows/block, 4 waves, each
// wave owns a 16x64 tile; W1 staged per-128-K-half as bf16 hi/lo in LDS
// (K-major, pitch 136 => 2-way bank alias = free, b128 reads); x loaded
// global->reg with zero lane redundancy + 1-step prefetch. A/B fragments use
// the SAME (group,elem)->k packing so the K-order convention cancels.

#define HIDC 64
#define FILL_CH 4096
#define WPITCH 136   // 128 + 8 pad (bf16 elems); 16B-aligned rows (136 = 17*8)

typedef unsigned short u16;
typedef short short8 __attribute__((ext_vector_type(8)));
typedef float f32x4 __attribute__((ext_vector_type(4)));

__device__ inline u16 f2bf(float f) {
    union { float f; unsigned int u; } v; v.f = f;
    unsigned int u = v.u;
    u += 0x7FFFu + ((u >> 16) & 1u);     // round-to-nearest-even
    return (u16)(u >> 16);
}
__device__ inline float bf2f(u16 b) {
    union { unsigned int u; float f; } v; v.u = ((unsigned int)b) << 16;
    return v.f;
}

// ---------------- degree ----------------
__global__ void k_deg(const int* __restrict__ col, int* __restrict__ deg, int E) {
    int e = blockIdx.x * blockDim.x + threadIdx.x;
    if (e < E) atomicAdd(&deg[col[e]], 1);
}

// ---------------- block exclusive scan helper (256 threads) ----------------
__device__ inline void blockExScan256(int v, int tid, int* ex_out, int* tot_out,
                                      volatile int* wsum) {
    int lane = tid & 63, w = tid >> 6;
    int inc = v;
    #pragma unroll
    for (int d = 1; d < 64; d <<= 1) {
        int t = __shfl_up(inc, d, 64);
        if (lane >= d) inc += t;
    }
    if (lane == 63) wsum[w] = inc;
    __syncthreads();
    int wbase = 0;
    #pragma unroll
    for (int k = 0; k < 4; ++k) if (k < w) wbase += wsum[k];
    *ex_out = wbase + inc - v;
    *tot_out = wsum[0] + wsum[1] + wsum[2] + wsum[3];
    __syncthreads();
}

__global__ void k_scanA(const int* __restrict__ deg, int* __restrict__ bsum, int N) {
    __shared__ int wsum[4];
    int i = blockIdx.x * blockDim.x + threadIdx.x;
    int v = (i < N) ? deg[i] : 0;
    int ex, tot;
    blockExScan256(v, threadIdx.x, &ex, &tot, wsum);
    if (threadIdx.x == 0) bsum[blockIdx.x] = tot;
}

__global__ void k_scanB(int* __restrict__ bsum, int nb) {
    __shared__ int wsum[4];
    __shared__ int carry;
    if (threadIdx.x == 0) carry = 0;
    __syncthreads();
    for (int base = 0; base < nb; base += 256) {
        int i = base + threadIdx.x;
        int v = (i < nb) ? bsum[i] : 0;
        int ex, tot;
        blockExScan256(v, threadIdx.x, &ex, &tot, wsum);
        int c = carry;
        if (i < nb) bsum[i] = c + ex;
        __syncthreads();
        if (threadIdx.x == 0) carry = c + tot;
        __syncthreads();
    }
}

__global__ void k_scanC(const int* __restrict__ deg, const int* __restrict__ bsum,
                        float* __restrict__ dis, int* __restrict__ off,
                        int* __restrict__ cursor, int N) {
    __shared__ int wsum[4];
    int i = blockIdx.x * blockDim.x + threadIdx.x;
    int d = (i < N) ? deg[i] : 0;
    int ex, tot;
    blockExScan256(d, threadIdx.x, &ex, &tot, wsum);
    if (i < N) {
        int o = bsum[blockIdx.x] + ex;
        off[i] = o;
        cursor[i] = o;
        dis[i] = (d > 0) ? rsqrtf((float)d) : 0.0f;
    }
}

// ---------------- CSR fill, region-grouped (XCD locality) ----------------
__global__ void k_fill2(const int* __restrict__ row, const int* __restrict__ col,
                        int* __restrict__ cursor, int* __restrict__ csr_src,
                        int E, int regDiv) {
    const int g = blockIdx.x & 7;
    const int base = (blockIdx.x >> 3) * FILL_CH;
    #pragma unroll 4
    for (int i = threadIdx.x; i < FILL_CH; i += 256) {
        int e = base + i;
        if (e < E) {
            int c = col[e];
            if (c / regDiv == g) {
                int pos = atomicAdd(&cursor[c], 1);
                csr_src[pos] = row[e];
            }
        }
    }
}

// ---------------- h = relu(x @ W1 + b1) via MFMA; sh_bf = bf16(dis*h) ----------
// 64 rows/block, 4 waves; wave w owns rows [blk*64 + w*16, +16), all 64 cols.
// Per K-half (128): W1 half staged to LDS as bf16 hi/lo, K-major (wt[n][k]).
// A frag: lane l holds row (l&15), k = kst*32 + (l>>4)*8 + j (j=0..7) -> two
// float4 global loads, split to bf16 hi/lo. B frag: same (group,elem)->k map,
// one ds_read_b128 per (ntile, hi/lo). C/D: n = nt*16 + (l&15),
// m = (l>>4)*4 + reg  [measured layout, learn_hip m89].
__global__ __launch_bounds__(256, 4)
void k_mlp1(const float* __restrict__ x, const float* __restrict__ W1,
            const float* __restrict__ b1, const float* __restrict__ dis,
            float* __restrict__ h, u16* __restrict__ sh_bf, int N) {
    __shared__ __align__(16) u16 wsH[64 * WPITCH];   // ~17 KB
    __shared__ __align__(16) u16 wsL[64 * WPITCH];   // ~17 KB  (total ~34 KB)
    const int tid = threadIdx.x;
    const int w = tid >> 6;
    const int l = tid & 63;
    const int q = l >> 4;
    const int i = l & 15;

    int aRow = blockIdx.x * 64 + w * 16 + i;
    if (aRow > N - 1) aRow = N - 1;
    const float* xp = x + (size_t)aRow * 256 + q * 8;

    f32x4 acc[4];
    #pragma unroll
    for (int nt = 0; nt < 4; ++nt) acc[nt] = f32x4{0.f, 0.f, 0.f, 0.f};

    // issue first A loads before staging so they overlap the W1 stage
    float4 c0 = *(const float4*)(xp);
    float4 c1 = *(const float4*)(xp + 4);

    // stage W1 half 0 (k in [0,128)) transposed to bf16 hi/lo
    {
        const float4* src = (const float4*)(W1);
        #pragma unroll
        for (int it = 0; it < 8; ++it) {
            int idx = tid + 256 * it;            // float4 index into 128x64
            float4 v = src[idx];
            int k = idx >> 4;                    // 16 float4 per 64-col row
            int n = (idx & 15) * 4;
            float fv[4] = {v.x, v.y, v.z, v.w};
            #pragma unroll
            for (int c = 0; c < 4; ++c) {
                u16 hh = f2bf(fv[c]);
                wsH[(n + c) * WPITCH + k] = hh;
                wsL[(n + c) * WPITCH + k] = f2bf(fv[c] - bf2f(hh));
            }
        }
    }
    __syncthreads();

    #pragma unroll
    for (int kst = 0; kst < 8; ++kst) {
        if (kst == 4) {
            __syncthreads();                     // everyone done with half 0
            const float4* src = (const float4*)(W1 + 128 * HIDC);
            #pragma unroll
            for (int it = 0; it < 8; ++it) {
                int idx = tid + 256 * it;
                float4 v = src[idx];
                int k = idx >> 4;
                int n = (idx & 15) * 4;
                float fv[4] = {v.x, v.y, v.z, v.w};
                #pragma unroll
                for (int c = 0; c < 4; ++c) {
                    u16 hh = f2bf(fv[c]);
                    wsH[(n + c) * WPITCH + k] = hh;
                    wsL[(n + c) * WPITCH + k] = f2bf(fv[c] - bf2f(hh));
                }
            }
            __syncthreads();
        }
        // prefetch next k-step's A (x loads are LDS-independent)
        float4 n0, n1;
        if (kst < 7) {
            n0 = *(const float4*)(xp + (kst + 1) * 32);
            n1 = *(const float4*)(xp + (kst + 1) * 32 + 4);
        }
        // split-convert current A to bf16 hi/lo fragments
        short8 ah, al;
        {
            float cf[8] = {c0.x, c0.y, c0.z, c0.w, c1.x, c1.y, c1.z, c1.w};
            #pragma unroll
            for (int j = 0; j < 8; ++j) {
                u16 hh = f2bf(cf[j]);
                ah[j] = (short)hh;
                al[j] = (short)f2bf(cf[j] - bf2f(hh));
            }
        }
        const int kl = (kst & 3) * 32 + q * 8;
        #pragma unroll
        for (int nt = 0; nt < 4; ++nt) {
            const int boff = (nt * 16 + i) * WPITCH + kl;
            short8 bh = *(const short8*)(&wsH[boff]);
            short8 bl = *(const short8*)(&wsL[boff]);
            acc[nt] = __builtin_amdgcn_mfma_f32_16x16x32_bf16(ah, bh, acc[nt], 0, 0, 0);
            acc[nt] = __builtin_amdgcn_mfma_f32_16x16x32_bf16(al, bh, acc[nt], 0, 0, 0);
            acc[nt] = __builtin_amdgcn_mfma_f32_16x16x32_bf16(ah, bl, acc[nt], 0, 0, 0);
        }
        c0 = n0; c1 = n1;
    }

    // epilogue: D row m = q*4 + r (within wave tile), col n = nt*16 + i
    const int rowBaseW = blockIdx.x * 64 + w * 16 + q * 4;
    float b1v[4];
    #pragma unroll
    for (int nt = 0; nt < 4; ++nt) b1v[nt] = b1[nt * 16 + i];
    #pragma unroll
    for (int r = 0; r < 4; ++r) {
        int m = rowBaseW + r;
        if (m < N) {
            float dm = dis[m];
            #pragma unroll
            for (int nt = 0; nt < 4; ++nt) {
                int n = nt * 16 + i;
                float vv = fmaxf(acc[nt][r] + b1v[nt], 0.0f);
                h[(size_t)m * HIDC + n] = vv;
                sh_bf[(size_t)m * HIDC + n] = f2bf(vv * dm);
            }
        }
    }
}

// ---------------- calc_M: wave per dest node, 4 edges/step, bf16 rows ----------------
__global__ void k_calcM(const int* __restrict__ csr_src, const int* __restrict__ off,
                        const int* __restrict__ deg, const float* __restrict__ dis,
                        const u16* __restrict__ scur, float* __restrict__ Mcsr,
                        float* __restrict__ alphaArr, int N) {
    int wave = (int)((blockIdx.x * (size_t)blockDim.x + threadIdx.x) >> 6);
    int lane = threadIdx.x & 63;
    if (wave >= N) return;
    const int c = wave;
    const int o = off[c];
    const int dg = deg[c];
    const int g = lane >> 4;     // edge group 0..3
    const int t = lane & 15;     // dim quad
    const float dc = dis[c];
    const ushort4 scb = *(const ushort4*)(scur + (size_t)c * HIDC + t * 4);
    const float scx = bf2f(scb.x), scy = bf2f(scb.y), scz = bf2f(scb.z), scw = bf2f(scb.w);
    float seg = 0.0f;
    for (int j = 0; j < dg; j += 4) {
        int jj = j + g;
        bool valid = jj < dg;
        int r = valid ? csr_src[o + jj] : c;     // r=c -> diff 0 for pad lanes
        const ushort4 srb = *(const ushort4*)(scur + (size_t)r * HIDC + t * 4);
        float dx = bf2f(srb.x) - scx, dy = bf2f(srb.y) - scy;
        float dz = bf2f(srb.z) - scz, dw = bf2f(srb.w) - scw;
        float s = fmaf(dx, dx, fmaf(dy, dy, fmaf(dz, dz, dw * dw)));
        s += __shfl_xor(s, 1, 64);
        s += __shfl_xor(s, 2, 64);
        s += __shfl_xor(s, 4, 64);
        s += __shfl_xor(s, 8, 64);
        float m = sqrtf(sqrtf(s));               // grad_norm^(P-2), P=2.5
        if (isinf(m)) m = 0.0f;
        if (valid) {
            if (t == 0) Mcsr[o + jj] = m;
            seg += m;
        }
    }
    seg += __shfl_xor(seg, 16, 64);
    seg += __shfl_xor(seg, 32, 64);
    if (lane == 0) alphaArr[c] = 1.0f / (dc * dc * seg + 0.08f);   // 2*MU/P
}

// ---------------- gather: out[c] = beta*h[c] + sum (alpha[r]*M*dc) * scur[r] ----------------
// outNext (f32) and/or soutNext (bf16 = dis*out); either may be null.
__global__ void k_gather(const int* __restrict__ csr_src, const int* __restrict__ off,
                         const int* __restrict__ deg, const float* __restrict__ dis,
                         const float* __restrict__ alphaArr, const float* __restrict__ Mcsr,
                         const u16* __restrict__ scur, const float* __restrict__ h,
                         float* __restrict__ outNext, u16* __restrict__ soutNext, int N) {
    int wave = (int)((blockIdx.x * (size_t)blockDim.x + threadIdx.x) >> 6);
    int lane = threadIdx.x & 63;
    if (wave >= N) return;
    const int c = wave;
    const int o = off[c];
    const int dg = deg[c];
    const int g = lane >> 4;
    const int t = lane & 15;
    const float dc = dis[c];
    float4 acc = make_float4(0.f, 0.f, 0.f, 0.f);
    for (int j = 0; j < dg; j += 4) {
        int jj = j + g;
        bool valid = jj < dg;
        int r = valid ? csr_src[o + jj] : c;
        float coef = valid ? (alphaArr[r] * Mcsr[o + jj] * dc) : 0.0f;
        const ushort4 srb = *(const ushort4*)(scur + (size_t)r * HIDC + t * 4);
        acc.x = fmaf(coef, bf2f(srb.x), acc.x);
        acc.y = fmaf(coef, bf2f(srb.y), acc.y);
        acc.z = fmaf(coef, bf2f(srb.z), acc.z);
        acc.w = fmaf(coef, bf2f(srb.w), acc.w);
    }
    acc.x += __shfl_xor(acc.x, 16, 64);
    acc.y += __shfl_xor(acc.y, 16, 64);
    acc.z += __shfl_xor(acc.z, 16, 64);
    acc.w += __shfl_xor(acc.w, 16, 64);
    acc.x += __shfl_xor(acc.x, 32, 64);
    acc.y += __shfl_xor(acc.y, 32, 64);
    acc.z += __shfl_xor(acc.z, 32, 64);
    acc.w += __shfl_xor(acc.w, 32, 64);
    if (g == 0) {
        float ba = 0.16f * alphaArr[c];          // beta = 4*MU/P * alpha
        const float4 hv = *(const float4*)(h + (size_t)c * HIDC + t * 4);
        float4 ov;
        ov.x = fmaf(ba, hv.x, acc.x);
        ov.y = fmaf(ba, hv.y, acc.y);
        ov.z = fmaf(ba, hv.z, acc.z);
        ov.w = fmaf(ba, hv.w, acc.w);
        if (outNext)  *(float4*)(outNext + (size_t)c * HIDC + t * 4) = ov;
        if (soutNext) {
            ushort4 sv;
            sv.x = f2bf(ov.x * dc); sv.y = f2bf(ov.y * dc);
            sv.z = f2bf(ov.z * dc); sv.w = f2bf(ov.w * dc);
            *(ushort4*)(soutNext + (size_t)c * HIDC + t * 4) = sv;
        }
    }
}

// ---------------- head: log_softmax(out @ W2 + b2) ----------------
__global__ void k_head(const float* __restrict__ out, const float* __restrict__ W2,
                       const float* __restrict__ b2, float* __restrict__ y,
                       int N, int OUT) {
    int wave = (int)((blockIdx.x * (size_t)blockDim.x + threadIdx.x) >> 6);
    int lane = threadIdx.x & 63;
    if (wave >= N) return;
    float acc = 0.0f;
    if (lane < OUT) {
        acc = b2[lane];
        #pragma unroll 8
        for (int k = 0; k < HIDC; ++k)
            acc = fmaf(out[(size_t)wave * HIDC + k], W2[k * OUT + lane], acc);
    }
    float v = (lane < OUT) ? acc : -INFINITY;
    #pragma unroll
    for (int sh = 32; sh; sh >>= 1) v = fmaxf(v, __shfl_xor(v, sh, 64));
    float ex = (lane < OUT) ? __expf(acc - v) : 0.0f;
    float s = ex;
    #pragma unroll
    for (int sh = 32; sh; sh >>= 1) s += __shfl_xor(s, sh, 64);
    if (lane < OUT) y[(size_t)wave * OUT + lane] = acc - v - __logf(s);
}

extern "C" void kernel_launch(void* const* d_in, const int* in_sizes, int n_in,
                              void* d_out, int out_size, void* d_ws, size_t ws_size,
                              hipStream_t stream) {
    const float* x  = (const float*)d_in[0];
    const int*   ei = (const int*)d_in[1];
    const float* W1 = (const float*)d_in[2];
    const float* b1 = (const float*)d_in[3];
    const float* W2 = (const float*)d_in[4];
    const float* b2 = (const float*)d_in[5];
    float* y = (float*)d_out;

    const int HID = in_sizes[3];            // 64
    const int IN  = in_sizes[2] / HID;      // 256
    const int OUT = in_sizes[5];            // 40
    const int N   = in_sizes[0] / IN;       // 100000
    const int E   = in_sizes[1] / 2;        // 1.6M
    const int* rowI = ei;
    const int* colI = ei + E;

    // workspace carve-up (float-granular; all counts even => 8B alignment holds)
    float* p = (float*)d_ws;
    float* dis   = p;  p += N;
    float* alpha = p;  p += N;
    float* Mcsr  = p;  p += E;
    float* h     = p;  p += (size_t)N * HID;     // raw MLP out (beta term)
    float* out2  = p;  p += (size_t)N * HID;     // final propagate output (f32)
    u16*   sh_bf = (u16*)p;  p += (size_t)N * HID / 2;   // bf16 dis*h
    u16*   sA_bf = (u16*)p;  p += (size_t)N * HID / 2;   // bf16 dis*out1
    int*   deg     = (int*)p;  p += N;
    int*   off     = (int*)p;  p += N;
    int*   cursor  = (int*)p;  p += N;
    int*   csr_src = (int*)p;  p += E;
    int*   bsum    = (int*)p;  p += (N + 255) / 256;

    const int TPB = 256;
    const int edgeBlocks = (E + TPB - 1) / TPB;
    const int nodeBlocks = (N + TPB - 1) / TPB;
    const int nodeWaveBlocks = (N + 3) / 4;    // 4 waves/block, wave per node
    const int regDiv = (N + 7) / 8;

    // CSR build: deg -> exclusive scan -> region-grouped fill
    hipMemsetAsync(deg, 0, sizeof(int) * N, stream);
    k_deg<<<edgeBlocks, TPB, 0, stream>>>(colI, deg, E);
    k_scanA<<<nodeBlocks, TPB, 0, stream>>>(deg, bsum, N);
    k_scanB<<<1, TPB, 0, stream>>>(bsum, nodeBlocks);
    k_scanC<<<nodeBlocks, TPB, 0, stream>>>(deg, bsum, dis, off, cursor, N);
    {
        int nch = (E + FILL_CH - 1) / FILL_CH;
        k_fill2<<<8 * nch, TPB, 0, stream>>>(rowI, colI, cursor, csr_src, E, regDiv);
    }

    // front MLP via MFMA (writes h f32 and sh_bf = bf16(dis*h)); 64 rows/block
    k_mlp1<<<(N + 63) / 64, TPB, 0, stream>>>(x, W1, b1, dis, h, sh_bf, N);

    // iteration 1: scur = sh_bf -> writes only sA_bf (raw out1 never consumed)
    k_calcM<<<nodeWaveBlocks, TPB, 0, stream>>>(csr_src, off, deg, dis, sh_bf, Mcsr, alpha, N);
    k_gather<<<nodeWaveBlocks, TPB, 0, stream>>>(csr_src, off, deg, dis, alpha, Mcsr,
                                                 sh_bf, h, (float*)nullptr, sA_bf, N);

    // iteration 2: scur = sA_bf -> writes raw out2 (f32)
    k_calcM<<<nodeWaveBlocks, TPB, 0, stream>>>(csr_src, off, deg, dis, sA_bf, Mcsr, alpha, N);
    k_gather<<<nodeWaveBlocks, TPB, 0, stream>>>(csr_src, off, deg, dis, alpha, Mcsr,
                                                 sA_bf, h, out2, (u16*)nullptr, N);

    // output head
    k_head<<<nodeWaveBlocks, TPB, 0, stream>>>(out2, W2, b2, y, N, OUT);
}

// Round 2
// 663.195 us; speedup vs baseline: 1.2042x; 1.1108x over previous
//
#include <hip/hip_runtime.h>
#include <math.h>

// pGNN on MI355X. N=100000, E=1.6M, IN=256, HID=64, OUT=40. MU=0.1, P=2.5, K=2.
// Round 10: head moved to the matrix pipe. k_head was 101 us, VALU-issue-bound
// (wave per node, 40/64 lanes, serial 64-iter scalar loop). Now: 4 waves/block
// x 16 rows/wave, W2 staged once in LDS as 48-col-padded K-major bf16 hi/lo,
// split-precision MFMA (ah*bh + al*bh + ah*bl) => ~f32 accuracy; log-softmax
// reduces within 16-lane groups via shfl_xor (C/D layout puts a row's 40
// logits in one i-group). Memory floor ~7 us; expect ~10-15 us.

#define HIDC 64
#define FILL_CH 4096
#define WPITCH 136   // 128 + 8 pad (bf16 elems); 16B-aligned rows (136 = 17*8)
#define W2P 72       // 64 + 8 pad for W2^T rows

typedef unsigned short u16;
typedef short short8 __attribute__((ext_vector_type(8)));
typedef float f32x4 __attribute__((ext_vector_type(4)));

__device__ inline u16 f2bf(float f) {
    union { float f; unsigned int u; } v; v.f = f;
    unsigned int u = v.u;
    u += 0x7FFFu + ((u >> 16) & 1u);     // round-to-nearest-even
    return (u16)(u >> 16);
}
__device__ inline float bf2f(u16 b) {
    union { unsigned int u; float f; } v; v.u = ((unsigned int)b) << 16;
    return v.f;
}

// ---------------- degree ----------------
__global__ void k_deg(const int* __restrict__ col, int* __restrict__ deg, int E) {
    int e = blockIdx.x * blockDim.x + threadIdx.x;
    if (e < E) atomicAdd(&deg[col[e]], 1);
}

// ---------------- block exclusive scan helper (256 threads) ----------------
__device__ inline void blockExScan256(int v, int tid, int* ex_out, int* tot_out,
                                      volatile int* wsum) {
    int lane = tid & 63, w = tid >> 6;
    int inc = v;
    #pragma unroll
    for (int d = 1; d < 64; d <<= 1) {
        int t = __shfl_up(inc, d, 64);
        if (lane >= d) inc += t;
    }
    if (lane == 63) wsum[w] = inc;
    __syncthreads();
    int wbase = 0;
    #pragma unroll
    for (int k = 0; k < 4; ++k) if (k < w) wbase += wsum[k];
    *ex_out = wbase + inc - v;
    *tot_out = wsum[0] + wsum[1] + wsum[2] + wsum[3];
    __syncthreads();
}

__global__ void k_scanA(const int* __restrict__ deg, int* __restrict__ bsum, int N) {
    __shared__ int wsum[4];
    int i = blockIdx.x * blockDim.x + threadIdx.x;
    int v = (i < N) ? deg[i] : 0;
    int ex, tot;
    blockExScan256(v, threadIdx.x, &ex, &tot, wsum);
    if (threadIdx.x == 0) bsum[blockIdx.x] = tot;
}

__global__ void k_scanB(int* __restrict__ bsum, int nb) {
    __shared__ int wsum[4];
    __shared__ int carry;
    if (threadIdx.x == 0) carry = 0;
    __syncthreads();
    for (int base = 0; base < nb; base += 256) {
        int i = base + threadIdx.x;
        int v = (i < nb) ? bsum[i] : 0;
        int ex, tot;
        blockExScan256(v, threadIdx.x, &ex, &tot, wsum);
        int c = carry;
        if (i < nb) bsum[i] = c + ex;
        __syncthreads();
        if (threadIdx.x == 0) carry = c + tot;
        __syncthreads();
    }
}

__global__ void k_scanC(const int* __restrict__ deg, const int* __restrict__ bsum,
                        float* __restrict__ dis, int* __restrict__ off,
                        int* __restrict__ cursor, int N) {
    __shared__ int wsum[4];
    int i = blockIdx.x * blockDim.x + threadIdx.x;
    int d = (i < N) ? deg[i] : 0;
    int ex, tot;
    blockExScan256(d, threadIdx.x, &ex, &tot, wsum);
    if (i < N) {
        int o = bsum[blockIdx.x] + ex;
        off[i] = o;
        cursor[i] = o;
        dis[i] = (d > 0) ? rsqrtf((float)d) : 0.0f;
    }
}

// ---------------- CSR fill, region-grouped (XCD locality) ----------------
__global__ void k_fill2(const int* __restrict__ row, const int* __restrict__ col,
                        int* __restrict__ cursor, int* __restrict__ csr_src,
                        int E, int regDiv) {
    const int g = blockIdx.x & 7;
    const int base = (blockIdx.x >> 3) * FILL_CH;
    #pragma unroll 4
    for (int i = threadIdx.x; i < FILL_CH; i += 256) {
        int e = base + i;
        if (e < E) {
            int c = col[e];
            if (c / regDiv == g) {
                int pos = atomicAdd(&cursor[c], 1);
                csr_src[pos] = row[e];
            }
        }
    }
}

// ---------------- h = relu(x @ W1 + b1) via MFMA; sh_bf = bf16(dis*h) ----------
// 64 rows/block, 4 waves; wave w owns rows [blk*64 + w*16, +16), all 64 cols.
// Per K-half (128): W1 half staged to LDS as bf16 hi/lo, K-major (wt[n][k]).
// A frag: lane l holds row (l&15), k = kst*32 + (l>>4)*8 + j (j=0..7) -> two
// float4 global loads, split to bf16 hi/lo. B frag: same (group,elem)->k map,
// one ds_read_b128 per (ntile, hi/lo). C/D: n = nt*16 + (l&15),
// m = (l>>4)*4 + reg  [measured layout, learn_hip m89].
__global__ __launch_bounds__(256, 4)
void k_mlp1(const float* __restrict__ x, const float* __restrict__ W1,
            const float* __restrict__ b1, const float* __restrict__ dis,
            float* __restrict__ h, u16* __restrict__ sh_bf, int N) {
    __shared__ __align__(16) u16 wsH[64 * WPITCH];   // ~17 KB
    __shared__ __align__(16) u16 wsL[64 * WPITCH];   // ~17 KB  (total ~34 KB)
    const int tid = threadIdx.x;
    const int w = tid >> 6;
    const int l = tid & 63;
    const int q = l >> 4;
    const int i = l & 15;

    int aRow = blockIdx.x * 64 + w * 16 + i;
    if (aRow > N - 1) aRow = N - 1;
    const float* xp = x + (size_t)aRow * 256 + q * 8;

    f32x4 acc[4];
    #pragma unroll
    for (int nt = 0; nt < 4; ++nt) acc[nt] = f32x4{0.f, 0.f, 0.f, 0.f};

    // issue first A loads before staging so they overlap the W1 stage
    float4 c0 = *(const float4*)(xp);
    float4 c1 = *(const float4*)(xp + 4);

    // stage W1 half 0 (k in [0,128)) transposed to bf16 hi/lo
    {
        const float4* src = (const float4*)(W1);
        #pragma unroll
        for (int it = 0; it < 8; ++it) {
            int idx = tid + 256 * it;            // float4 index into 128x64
            float4 v = src[idx];
            int k = idx >> 4;                    // 16 float4 per 64-col row
            int n = (idx & 15) * 4;
            float fv[4] = {v.x, v.y, v.z, v.w};
            #pragma unroll
            for (int c = 0; c < 4; ++c) {
                u16 hh = f2bf(fv[c]);
                wsH[(n + c) * WPITCH + k] = hh;
                wsL[(n + c) * WPITCH + k] = f2bf(fv[c] - bf2f(hh));
            }
        }
    }
    __syncthreads();

    #pragma unroll
    for (int kst = 0; kst < 8; ++kst) {
        if (kst == 4) {
            __syncthreads();                     // everyone done with half 0
            const float4* src = (const float4*)(W1 + 128 * HIDC);
            #pragma unroll
            for (int it = 0; it < 8; ++it) {
                int idx = tid + 256 * it;
                float4 v = src[idx];
                int k = idx >> 4;
                int n = (idx & 15) * 4;
                float fv[4] = {v.x, v.y, v.z, v.w};
                #pragma unroll
                for (int c = 0; c < 4; ++c) {
                    u16 hh = f2bf(fv[c]);
                    wsH[(n + c) * WPITCH + k] = hh;
                    wsL[(n + c) * WPITCH + k] = f2bf(fv[c] - bf2f(hh));
                }
            }
            __syncthreads();
        }
        // prefetch next k-step's A (x loads are LDS-independent)
        float4 n0, n1;
        if (kst < 7) {
            n0 = *(const float4*)(xp + (kst + 1) * 32);
            n1 = *(const float4*)(xp + (kst + 1) * 32 + 4);
        }
        // split-convert current A to bf16 hi/lo fragments
        short8 ah, al;
        {
            float cf[8] = {c0.x, c0.y, c0.z, c0.w, c1.x, c1.y, c1.z, c1.w};
            #pragma unroll
            for (int j = 0; j < 8; ++j) {
                u16 hh = f2bf(cf[j]);
                ah[j] = (short)hh;
                al[j] = (short)f2bf(cf[j] - bf2f(hh));
            }
        }
        const int kl = (kst & 3) * 32 + q * 8;
        #pragma unroll
        for (int nt = 0; nt < 4; ++nt) {
            const int boff = (nt * 16 + i) * WPITCH + kl;
            short8 bh = *(const short8*)(&wsH[boff]);
            short8 bl = *(const short8*)(&wsL[boff]);
            acc[nt] = __builtin_amdgcn_mfma_f32_16x16x32_bf16(ah, bh, acc[nt], 0, 0, 0);
            acc[nt] = __builtin_amdgcn_mfma_f32_16x16x32_bf16(al, bh, acc[nt], 0, 0, 0);
            acc[nt] = __builtin_amdgcn_mfma_f32_16x16x32_bf16(ah, bl, acc[nt], 0, 0, 0);
        }
        c0 = n0; c1 = n1;
    }

    // epilogue: D row m = q*4 + r (within wave tile), col n = nt*16 + i
    const int rowBaseW = blockIdx.x * 64 + w * 16 + q * 4;
    float b1v[4];
    #pragma unroll
    for (int nt = 0; nt < 4; ++nt) b1v[nt] = b1[nt * 16 + i];
    #pragma unroll
    for (int r = 0; r < 4; ++r) {
        int m = rowBaseW + r;
        if (m < N) {
            float dm = dis[m];
            #pragma unroll
            for (int nt = 0; nt < 4; ++nt) {
                int n = nt * 16 + i;
                float vv = fmaxf(acc[nt][r] + b1v[nt], 0.0f);
                h[(size_t)m * HIDC + n] = vv;
                sh_bf[(size_t)m * HIDC + n] = f2bf(vv * dm);
            }
        }
    }
}

// ---------------- calc_M: wave per dest node, 4 edges/step, bf16 rows ----------------
__global__ void k_calcM(const int* __restrict__ csr_src, const int* __restrict__ off,
                        const int* __restrict__ deg, const float* __restrict__ dis,
                        const u16* __restrict__ scur, float* __restrict__ Mcsr,
                        float* __restrict__ alphaArr, int N) {
    int wave = (int)((blockIdx.x * (size_t)blockDim.x + threadIdx.x) >> 6);
    int lane = threadIdx.x & 63;
    if (wave >= N) return;
    const int c = wave;
    const int o = off[c];
    const int dg = deg[c];
    const int g = lane >> 4;     // edge group 0..3
    const int t = lane & 15;     // dim quad
    const float dc = dis[c];
    const ushort4 scb = *(const ushort4*)(scur + (size_t)c * HIDC + t * 4);
    const float scx = bf2f(scb.x), scy = bf2f(scb.y), scz = bf2f(scb.z), scw = bf2f(scb.w);
    float seg = 0.0f;
    for (int j = 0; j < dg; j += 4) {
        int jj = j + g;
        bool valid = jj < dg;
        int r = valid ? csr_src[o + jj] : c;     // r=c -> diff 0 for pad lanes
        const ushort4 srb = *(const ushort4*)(scur + (size_t)r * HIDC + t * 4);
        float dx = bf2f(srb.x) - scx, dy = bf2f(srb.y) - scy;
        float dz = bf2f(srb.z) - scz, dw = bf2f(srb.w) - scw;
        float s = fmaf(dx, dx, fmaf(dy, dy, fmaf(dz, dz, dw * dw)));
        s += __shfl_xor(s, 1, 64);
        s += __shfl_xor(s, 2, 64);
        s += __shfl_xor(s, 4, 64);
        s += __shfl_xor(s, 8, 64);
        float m = sqrtf(sqrtf(s));               // grad_norm^(P-2), P=2.5
        if (isinf(m)) m = 0.0f;
        if (valid) {
            if (t == 0) Mcsr[o + jj] = m;
            seg += m;
        }
    }
    seg += __shfl_xor(seg, 16, 64);
    seg += __shfl_xor(seg, 32, 64);
    if (lane == 0) alphaArr[c] = 1.0f / (dc * dc * seg + 0.08f);   // 2*MU/P
}

// ---------------- gather: out[c] = beta*h[c] + sum (alpha[r]*M*dc) * scur[r] ----------------
// outNext (f32) and/or soutNext (bf16 = dis*out); either may be null.
__global__ void k_gather(const int* __restrict__ csr_src, const int* __restrict__ off,
                         const int* __restrict__ deg, const float* __restrict__ dis,
                         const float* __restrict__ alphaArr, const float* __restrict__ Mcsr,
                         const u16* __restrict__ scur, const float* __restrict__ h,
                         float* __restrict__ outNext, u16* __restrict__ soutNext, int N) {
    int wave = (int)((blockIdx.x * (size_t)blockDim.x + threadIdx.x) >> 6);
    int lane = threadIdx.x & 63;
    if (wave >= N) return;
    const int c = wave;
    const int o = off[c];
    const int dg = deg[c];
    const int g = lane >> 4;
    const int t = lane & 15;
    const float dc = dis[c];
    float4 acc = make_float4(0.f, 0.f, 0.f, 0.f);
    for (int j = 0; j < dg; j += 4) {
        int jj = j + g;
        bool valid = jj < dg;
        int r = valid ? csr_src[o + jj] : c;
        float coef = valid ? (alphaArr[r] * Mcsr[o + jj] * dc) : 0.0f;
        const ushort4 srb = *(const ushort4*)(scur + (size_t)r * HIDC + t * 4);
        acc.x = fmaf(coef, bf2f(srb.x), acc.x);
        acc.y = fmaf(coef, bf2f(srb.y), acc.y);
        acc.z = fmaf(coef, bf2f(srb.z), acc.z);
        acc.w = fmaf(coef, bf2f(srb.w), acc.w);
    }
    acc.x += __shfl_xor(acc.x, 16, 64);
    acc.y += __shfl_xor(acc.y, 16, 64);
    acc.z += __shfl_xor(acc.z, 16, 64);
    acc.w += __shfl_xor(acc.w, 16, 64);
    acc.x += __shfl_xor(acc.x, 32, 64);
    acc.y += __shfl_xor(acc.y, 32, 64);
    acc.z += __shfl_xor(acc.z, 32, 64);
    acc.w += __shfl_xor(acc.w, 32, 64);
    if (g == 0) {
        float ba = 0.16f * alphaArr[c];          // beta = 4*MU/P * alpha
        const float4 hv = *(const float4*)(h + (size_t)c * HIDC + t * 4);
        float4 ov;
        ov.x = fmaf(ba, hv.x, acc.x);
        ov.y = fmaf(ba, hv.y, acc.y);
        ov.z = fmaf(ba, hv.z, acc.z);
        ov.w = fmaf(ba, hv.w, acc.w);
        if (outNext)  *(float4*)(outNext + (size_t)c * HIDC + t * 4) = ov;
        if (soutNext) {
            ushort4 sv;
            sv.x = f2bf(ov.x * dc); sv.y = f2bf(ov.y * dc);
            sv.z = f2bf(ov.z * dc); sv.w = f2bf(ov.w * dc);
            *(ushort4*)(soutNext + (size_t)c * HIDC + t * 4) = sv;
        }
    }
}

// ---------------- head: log_softmax(out @ W2 + b2) via MFMA ----------------
// 64 rows/block, 4 waves x 16 rows. W2^T staged once: [48 padded cols][64 k]
// bf16 hi/lo (13.5 KB). K=64 -> 2 ksteps; 3 n-tiles (40 cols -> 48).
// Split-precision: ah*bh + al*bh + ah*bl. C/D: row m=(l>>4)*4+reg,
// col n = nt*16 + (l&15) -> each row's logits live in one 16-lane i-group,
// so max/sum reduce = shfl_xor {1,2,4,8}.
__global__ __launch_bounds__(256, 4)
void k_head(const float* __restrict__ out, const float* __restrict__ W2,
            const float* __restrict__ b2, float* __restrict__ y,
            int N, int OUT) {
    __shared__ __align__(16) u16 wtH[48 * W2P];   // 6.75 KB
    __shared__ __align__(16) u16 wtL[48 * W2P];   // 6.75 KB
    const int tid = threadIdx.x;
    const int w = tid >> 6;
    const int l = tid & 63;
    const int q = l >> 4;
    const int i = l & 15;

    // stage W2^T (48 padded cols x 64 k) as bf16 hi/lo
    for (int idx = tid; idx < 48 * 64; idx += 256) {
        int n = idx >> 6, k = idx & 63;
        float v = (n < OUT) ? W2[k * OUT + n] : 0.0f;
        u16 hh = f2bf(v);
        wtH[n * W2P + k] = hh;
        wtL[n * W2P + k] = f2bf(v - bf2f(hh));
    }
    __syncthreads();

    int aRow = blockIdx.x * 64 + w * 16 + i;
    if (aRow > N - 1) aRow = N - 1;
    const float* op = out + (size_t)aRow * HIDC + q * 8;

    f32x4 acc[3];
    #pragma unroll
    for (int nt = 0; nt < 3; ++nt) acc[nt] = f32x4{0.f, 0.f, 0.f, 0.f};

    #pragma unroll
    for (int kst = 0; kst < 2; ++kst) {
        float4 c0 = *(const float4*)(op + kst * 32);
        float4 c1 = *(const float4*)(op + kst * 32 + 4);
        short8 ah, al;
        {
            float cf[8] = {c0.x, c0.y, c0.z, c0.w, c1.x, c1.y, c1.z, c1.w};
            #pragma unroll
            for (int j = 0; j < 8; ++j) {
                u16 hh = f2bf(cf[j]);
                ah[j] = (short)hh;
                al[j] = (short)f2bf(cf[j] - bf2f(hh));
            }
        }
        const int kl = kst * 32 + q * 8;
        #pragma unroll
        for (int nt = 0; nt < 3; ++nt) {
            const int boff = (nt * 16 + i) * W2P + kl;
            short8 bh = *(const short8*)(&wtH[boff]);
            short8 bl = *(const short8*)(&wtL[boff]);
            acc[nt] = __builtin_amdgcn_mfma_f32_16x16x32_bf16(ah, bh, acc[nt], 0, 0, 0);
            acc[nt] = __builtin_amdgcn_mfma_f32_16x16x32_bf16(al, bh, acc[nt], 0, 0, 0);
            acc[nt] = __builtin_amdgcn_mfma_f32_16x16x32_bf16(ah, bl, acc[nt], 0, 0, 0);
        }
    }

    float bv[3];
    #pragma unroll
    for (int nt = 0; nt < 3; ++nt) {
        int n = nt * 16 + i;
        bv[nt] = (n < OUT) ? b2[n] : 0.0f;
    }
    const int rowBaseW = blockIdx.x * 64 + w * 16 + q * 4;
    #pragma unroll
    for (int r = 0; r < 4; ++r) {
        int m = rowBaseW + r;
        float lg[3];
        #pragma unroll
        for (int nt = 0; nt < 3; ++nt) lg[nt] = acc[nt][r] + bv[nt];
        bool v2 = (32 + i) < OUT;                 // nt=2 validity (nt 0,1 always valid)
        float mx = fmaxf(lg[0], lg[1]);
        if (v2) mx = fmaxf(mx, lg[2]);
        #pragma unroll
        for (int sh = 1; sh < 16; sh <<= 1) mx = fmaxf(mx, __shfl_xor(mx, sh, 64));
        float e0 = __expf(lg[0] - mx);
        float e1 = __expf(lg[1] - mx);
        float e2 = v2 ? __expf(lg[2] - mx) : 0.0f;
        float s = e0 + e1 + e2;
        #pragma unroll
        for (int sh = 1; sh < 16; sh <<= 1) s += __shfl_xor(s, sh, 64);
        float ls = mx + __logf(s);
        if (m < N) {
            y[(size_t)m * OUT + i]      = lg[0] - ls;
            y[(size_t)m * OUT + 16 + i] = lg[1] - ls;
            if (v2) y[(size_t)m * OUT + 32 + i] = lg[2] - ls;
        }
    }
}

extern "C" void kernel_launch(void* const* d_in, const int* in_sizes, int n_in,
                              void* d_out, int out_size, void* d_ws, size_t ws_size,
                              hipStream_t stream) {
    const float* x  = (const float*)d_in[0];
    const int*   ei = (const int*)d_in[1];
    const float* W1 = (const float*)d_in[2];
    const float* b1 = (const float*)d_in[3];
    const float* W2 = (const float*)d_in[4];
    const float* b2 = (const float*)d_in[5];
    float* y = (float*)d_out;

    const int HID = in_sizes[3];            // 64
    const int IN  = in_sizes[2] / HID;      // 256
    const int OUT = in_sizes[5];            // 40
    const int N   = in_sizes[0] / IN;       // 100000
    const int E   = in_sizes[1] / 2;        // 1.6M
    const int* rowI = ei;
    const int* colI = ei + E;

    // workspace carve-up (float-granular; all counts even => 8B alignment holds)
    float* p = (float*)d_ws;
    float* dis   = p;  p += N;
    float* alpha = p;  p += N;
    float* Mcsr  = p;  p += E;
    float* h     = p;  p += (size_t)N * HID;     // raw MLP out (beta term)
    float* out2  = p;  p += (size_t)N * HID;     // final propagate output (f32)
    u16*   sh_bf = (u16*)p;  p += (size_t)N * HID / 2;   // bf16 dis*h
    u16*   sA_bf = (u16*)p;  p += (size_t)N * HID / 2;   // bf16 dis*out1
    int*   deg     = (int*)p;  p += N;
    int*   off     = (int*)p;  p += N;
    int*   cursor  = (int*)p;  p += N;
    int*   csr_src = (int*)p;  p += E;
    int*   bsum    = (int*)p;  p += (N + 255) / 256;

    const int TPB = 256;
    const int edgeBlocks = (E + TPB - 1) / TPB;
    const int nodeBlocks = (N + TPB - 1) / TPB;
    const int nodeWaveBlocks = (N + 3) / 4;    // 4 waves/block, wave per node
    const int regDiv = (N + 7) / 8;

    // CSR build: deg -> exclusive scan -> region-grouped fill
    hipMemsetAsync(deg, 0, sizeof(int) * N, stream);
    k_deg<<<edgeBlocks, TPB, 0, stream>>>(colI, deg, E);
    k_scanA<<<nodeBlocks, TPB, 0, stream>>>(deg, bsum, N);
    k_scanB<<<1, TPB, 0, stream>>>(bsum, nodeBlocks);
    k_scanC<<<nodeBlocks, TPB, 0, stream>>>(deg, bsum, dis, off, cursor, N);
    {
        int nch = (E + FILL_CH - 1) / FILL_CH;
        k_fill2<<<8 * nch, TPB, 0, stream>>>(rowI, colI, cursor, csr_src, E, regDiv);
    }

    // front MLP via MFMA (writes h f32 and sh_bf = bf16(dis*h)); 64 rows/block
    k_mlp1<<<(N + 63) / 64, TPB, 0, stream>>>(x, W1, b1, dis, h, sh_bf, N);

    // iteration 1: scur = sh_bf -> writes only sA_bf (raw out1 never consumed)
    k_calcM<<<nodeWaveBlocks, TPB, 0, stream>>>(csr_src, off, deg, dis, sh_bf, Mcsr, alpha, N);
    k_gather<<<nodeWaveBlocks, TPB, 0, stream>>>(csr_src, off, deg, dis, alpha, Mcsr,
                                                 sh_bf, h, (float*)nullptr, sA_bf, N);

    // iteration 2: scur = sA_bf -> writes raw out2 (f32)
    k_calcM<<<nodeWaveBlocks, TPB, 0, stream>>>(csr_src, off, deg, dis, sA_bf, Mcsr, alpha, N);
    k_gather<<<nodeWaveBlocks, TPB, 0, stream>>>(csr_src, off, deg, dis, alpha, Mcsr,
                                                 sA_bf, h, out2, (u16*)nullptr, N);

    // output head via MFMA; 64 rows/block
    k_head<<<(N + 63) / 64, TPB, 0, stream>>>(out2, W2, b2, y, N, OUT);
}

// Round 3
// 551.870 us; speedup vs baseline: 1.4471x; 1.2017x over previous
//
#include <hip/hip_runtime.h>
#include <math.h>

// pGNN on MI355X. N=100000, E=1.6M, IN=256, HID=64, OUT=40. MU=0.1, P=2.5, K=2.
// Round 11: edge kernels (calcM/gather, ~330us = 50% of pipeline) rebuilt for
// vmem-address throughput. Old: 4 edges/step, 16 lanes x 8B rows, per-step
// index/alpha/M loads 16-way lane-redundant (~4 vmem instr x 64 addr per 4
// edges -> TA-bound ~50us/dispatch). New: 8 lanes/edge x 8 edges/step
// (ushort8 16B/lane -> 1 instr = 8 rows), indices+coefs batch-loaded 64-wide
// coalesced once per chunk and broadcast via shfl. Padding uses r=c (diff=0,
// m=0) / coef=0 -> branchless hot loop. Predicted: gather 87->~42us.

#define HIDC 64
#define FILL_CH 4096
#define WPITCH 136   // 128 + 8 pad (bf16 elems); 16B-aligned rows (136 = 17*8)
#define W2P 72       // 64 + 8 pad for W2^T rows

typedef unsigned short u16;
typedef short short8 __attribute__((ext_vector_type(8)));
typedef unsigned short ushort8 __attribute__((ext_vector_type(8)));
typedef float f32x4 __attribute__((ext_vector_type(4)));

__device__ inline u16 f2bf(float f) {
    union { float f; unsigned int u; } v; v.f = f;
    unsigned int u = v.u;
    u += 0x7FFFu + ((u >> 16) & 1u);     // round-to-nearest-even
    return (u16)(u >> 16);
}
__device__ inline float bf2f(u16 b) {
    union { unsigned int u; float f; } v; v.u = ((unsigned int)b) << 16;
    return v.f;
}

// ---------------- degree ----------------
__global__ void k_deg(const int* __restrict__ col, int* __restrict__ deg, int E) {
    int e = blockIdx.x * blockDim.x + threadIdx.x;
    if (e < E) atomicAdd(&deg[col[e]], 1);
}

// ---------------- block exclusive scan helper (256 threads) ----------------
__device__ inline void blockExScan256(int v, int tid, int* ex_out, int* tot_out,
                                      volatile int* wsum) {
    int lane = tid & 63, w = tid >> 6;
    int inc = v;
    #pragma unroll
    for (int d = 1; d < 64; d <<= 1) {
        int t = __shfl_up(inc, d, 64);
        if (lane >= d) inc += t;
    }
    if (lane == 63) wsum[w] = inc;
    __syncthreads();
    int wbase = 0;
    #pragma unroll
    for (int k = 0; k < 4; ++k) if (k < w) wbase += wsum[k];
    *ex_out = wbase + inc - v;
    *tot_out = wsum[0] + wsum[1] + wsum[2] + wsum[3];
    __syncthreads();
}

__global__ void k_scanA(const int* __restrict__ deg, int* __restrict__ bsum, int N) {
    __shared__ int wsum[4];
    int i = blockIdx.x * blockDim.x + threadIdx.x;
    int v = (i < N) ? deg[i] : 0;
    int ex, tot;
    blockExScan256(v, threadIdx.x, &ex, &tot, wsum);
    if (threadIdx.x == 0) bsum[blockIdx.x] = tot;
}

__global__ void k_scanB(int* __restrict__ bsum, int nb) {
    __shared__ int wsum[4];
    __shared__ int carry;
    if (threadIdx.x == 0) carry = 0;
    __syncthreads();
    for (int base = 0; base < nb; base += 256) {
        int i = base + threadIdx.x;
        int v = (i < nb) ? bsum[i] : 0;
        int ex, tot;
        blockExScan256(v, threadIdx.x, &ex, &tot, wsum);
        int c = carry;
        if (i < nb) bsum[i] = c + ex;
        __syncthreads();
        if (threadIdx.x == 0) carry = c + tot;
        __syncthreads();
    }
}

__global__ void k_scanC(const int* __restrict__ deg, const int* __restrict__ bsum,
                        float* __restrict__ dis, int* __restrict__ off,
                        int* __restrict__ cursor, int N) {
    __shared__ int wsum[4];
    int i = blockIdx.x * blockDim.x + threadIdx.x;
    int d = (i < N) ? deg[i] : 0;
    int ex, tot;
    blockExScan256(d, threadIdx.x, &ex, &tot, wsum);
    if (i < N) {
        int o = bsum[blockIdx.x] + ex;
        off[i] = o;
        cursor[i] = o;
        dis[i] = (d > 0) ? rsqrtf((float)d) : 0.0f;
    }
}

// ---------------- CSR fill, region-grouped (XCD locality) ----------------
__global__ void k_fill2(const int* __restrict__ row, const int* __restrict__ col,
                        int* __restrict__ cursor, int* __restrict__ csr_src,
                        int E, int regDiv) {
    const int g = blockIdx.x & 7;
    const int base = (blockIdx.x >> 3) * FILL_CH;
    #pragma unroll 4
    for (int i = threadIdx.x; i < FILL_CH; i += 256) {
        int e = base + i;
        if (e < E) {
            int c = col[e];
            if (c / regDiv == g) {
                int pos = atomicAdd(&cursor[c], 1);
                csr_src[pos] = row[e];
            }
        }
    }
}

// ---------------- h = relu(x @ W1 + b1) via MFMA; sh_bf = bf16(dis*h) ----------
__global__ __launch_bounds__(256, 4)
void k_mlp1(const float* __restrict__ x, const float* __restrict__ W1,
            const float* __restrict__ b1, const float* __restrict__ dis,
            float* __restrict__ h, u16* __restrict__ sh_bf, int N) {
    __shared__ __align__(16) u16 wsH[64 * WPITCH];   // ~17 KB
    __shared__ __align__(16) u16 wsL[64 * WPITCH];   // ~17 KB  (total ~34 KB)
    const int tid = threadIdx.x;
    const int w = tid >> 6;
    const int l = tid & 63;
    const int q = l >> 4;
    const int i = l & 15;

    int aRow = blockIdx.x * 64 + w * 16 + i;
    if (aRow > N - 1) aRow = N - 1;
    const float* xp = x + (size_t)aRow * 256 + q * 8;

    f32x4 acc[4];
    #pragma unroll
    for (int nt = 0; nt < 4; ++nt) acc[nt] = f32x4{0.f, 0.f, 0.f, 0.f};

    // issue first A loads before staging so they overlap the W1 stage
    float4 c0 = *(const float4*)(xp);
    float4 c1 = *(const float4*)(xp + 4);

    // stage W1 half 0 (k in [0,128)) transposed to bf16 hi/lo
    {
        const float4* src = (const float4*)(W1);
        #pragma unroll
        for (int it = 0; it < 8; ++it) {
            int idx = tid + 256 * it;            // float4 index into 128x64
            float4 v = src[idx];
            int k = idx >> 4;                    // 16 float4 per 64-col row
            int n = (idx & 15) * 4;
            float fv[4] = {v.x, v.y, v.z, v.w};
            #pragma unroll
            for (int c = 0; c < 4; ++c) {
                u16 hh = f2bf(fv[c]);
                wsH[(n + c) * WPITCH + k] = hh;
                wsL[(n + c) * WPITCH + k] = f2bf(fv[c] - bf2f(hh));
            }
        }
    }
    __syncthreads();

    #pragma unroll
    for (int kst = 0; kst < 8; ++kst) {
        if (kst == 4) {
            __syncthreads();                     // everyone done with half 0
            const float4* src = (const float4*)(W1 + 128 * HIDC);
            #pragma unroll
            for (int it = 0; it < 8; ++it) {
                int idx = tid + 256 * it;
                float4 v = src[idx];
                int k = idx >> 4;
                int n = (idx & 15) * 4;
                float fv[4] = {v.x, v.y, v.z, v.w};
                #pragma unroll
                for (int c = 0; c < 4; ++c) {
                    u16 hh = f2bf(fv[c]);
                    wsH[(n + c) * WPITCH + k] = hh;
                    wsL[(n + c) * WPITCH + k] = f2bf(fv[c] - bf2f(hh));
                }
            }
            __syncthreads();
        }
        // prefetch next k-step's A (x loads are LDS-independent)
        float4 n0, n1;
        if (kst < 7) {
            n0 = *(const float4*)(xp + (kst + 1) * 32);
            n1 = *(const float4*)(xp + (kst + 1) * 32 + 4);
        }
        // split-convert current A to bf16 hi/lo fragments
        short8 ah, al;
        {
            float cf[8] = {c0.x, c0.y, c0.z, c0.w, c1.x, c1.y, c1.z, c1.w};
            #pragma unroll
            for (int j = 0; j < 8; ++j) {
                u16 hh = f2bf(cf[j]);
                ah[j] = (short)hh;
                al[j] = (short)f2bf(cf[j] - bf2f(hh));
            }
        }
        const int kl = (kst & 3) * 32 + q * 8;
        #pragma unroll
        for (int nt = 0; nt < 4; ++nt) {
            const int boff = (nt * 16 + i) * WPITCH + kl;
            short8 bh = *(const short8*)(&wsH[boff]);
            short8 bl = *(const short8*)(&wsL[boff]);
            acc[nt] = __builtin_amdgcn_mfma_f32_16x16x32_bf16(ah, bh, acc[nt], 0, 0, 0);
            acc[nt] = __builtin_amdgcn_mfma_f32_16x16x32_bf16(al, bh, acc[nt], 0, 0, 0);
            acc[nt] = __builtin_amdgcn_mfma_f32_16x16x32_bf16(ah, bl, acc[nt], 0, 0, 0);
        }
        c0 = n0; c1 = n1;
    }

    // epilogue: D row m = q*4 + r (within wave tile), col n = nt*16 + i
    const int rowBaseW = blockIdx.x * 64 + w * 16 + q * 4;
    float b1v[4];
    #pragma unroll
    for (int nt = 0; nt < 4; ++nt) b1v[nt] = b1[nt * 16 + i];
    #pragma unroll
    for (int r = 0; r < 4; ++r) {
        int m = rowBaseW + r;
        if (m < N) {
            float dm = dis[m];
            #pragma unroll
            for (int nt = 0; nt < 4; ++nt) {
                int n = nt * 16 + i;
                float vv = fmaxf(acc[nt][r] + b1v[nt], 0.0f);
                h[(size_t)m * HIDC + n] = vv;
                sh_bf[(size_t)m * HIDC + n] = f2bf(vv * dm);
            }
        }
    }
}

// ---------------- calc_M: wave per dest node, 8 lanes/edge x 8 edges/step ----
// Chunk prologue: 64 coalesced csr_src loads; per step one ushort8 row load
// fetches 8 rows (16B/lane). Pad edges use r=c -> diff==0 -> m==0, so seg and
// the k-reduce need no masking. seg accumulated per group (identical across k
// lanes), reduced over g bits {8,16,32}.
__global__ void k_calcM(const int* __restrict__ csr_src, const int* __restrict__ off,
                        const int* __restrict__ deg, const float* __restrict__ dis,
                        const u16* __restrict__ scur, float* __restrict__ Mcsr,
                        float* __restrict__ alphaArr, int N) {
    int wave = (int)((blockIdx.x * (size_t)blockDim.x + threadIdx.x) >> 6);
    int lane = threadIdx.x & 63;
    if (wave >= N) return;
    const int c = wave;
    const int o = off[c];
    const int dg = deg[c];
    const int g = lane >> 3;     // edge subgroup 0..7
    const int k = lane & 7;      // dim octet 0..7
    const float dc = dis[c];
    float sc[8];
    {
        ushort8 scb = *(const ushort8*)(scur + (size_t)c * HIDC + k * 8);
        #pragma unroll
        for (int d = 0; d < 8; ++d) sc[d] = bf2f(scb[d]);
    }
    float seg = 0.0f;
    for (int base = 0; base < dg; base += 64) {
        int eI = base + lane;
        int rl = (eI < dg) ? csr_src[o + eI] : c;
        int nb = dg - base; if (nb > 64) nb = 64;
        for (int j = 0; j < nb; j += 8) {
            int r = __shfl(rl, j + g, 64);
            ushort8 srb = *(const ushort8*)(scur + (size_t)r * HIDC + k * 8);
            float s = 0.0f;
            #pragma unroll
            for (int d = 0; d < 8; ++d) {
                float df = bf2f(srb[d]) - sc[d];
                s = fmaf(df, df, s);
            }
            s += __shfl_xor(s, 1, 64);
            s += __shfl_xor(s, 2, 64);
            s += __shfl_xor(s, 4, 64);
            float m = sqrtf(sqrtf(s));           // grad_norm^(P-2), P=2.5
            if (isinf(m)) m = 0.0f;
            seg += m;                            // pad edges give m==0
            if (k == 0 && j + g < nb) Mcsr[o + base + j + g] = m;
        }
    }
    seg += __shfl_xor(seg, 8, 64);
    seg += __shfl_xor(seg, 16, 64);
    seg += __shfl_xor(seg, 32, 64);
    if (lane == 0) alphaArr[c] = 1.0f / (dc * dc * seg + 0.08f);   // 2*MU/P
}

// ---------------- gather: out[c] = beta*h[c] + sum (alpha[r]*M*dc) * scur[r] --
// Same 8x8 structure; coefs batch-computed 64-wide in the chunk prologue
// (coalesced Mcsr + one 64-wide random alpha gather) and shfl-broadcast.
__global__ void k_gather(const int* __restrict__ csr_src, const int* __restrict__ off,
                         const int* __restrict__ deg, const float* __restrict__ dis,
                         const float* __restrict__ alphaArr, const float* __restrict__ Mcsr,
                         const u16* __restrict__ scur, const float* __restrict__ h,
                         float* __restrict__ outNext, u16* __restrict__ soutNext, int N) {
    int wave = (int)((blockIdx.x * (size_t)blockDim.x + threadIdx.x) >> 6);
    int lane = threadIdx.x & 63;
    if (wave >= N) return;
    const int c = wave;
    const int o = off[c];
    const int dg = deg[c];
    const int g = lane >> 3;
    const int k = lane & 7;
    const float dc = dis[c];
    float acc[8];
    #pragma unroll
    for (int d = 0; d < 8; ++d) acc[d] = 0.0f;
    for (int base = 0; base < dg; base += 64) {
        int eI = base + lane;
        bool v = eI < dg;
        int rl = v ? csr_src[o + eI] : c;
        float cl = v ? (alphaArr[rl] * Mcsr[o + eI] * dc) : 0.0f;
        int nb = dg - base; if (nb > 64) nb = 64;
        for (int j = 0; j < nb; j += 8) {
            int r = __shfl(rl, j + g, 64);
            float ce = __shfl(cl, j + g, 64);
            ushort8 srb = *(const ushort8*)(scur + (size_t)r * HIDC + k * 8);
            #pragma unroll
            for (int d = 0; d < 8; ++d)
                acc[d] = fmaf(ce, bf2f(srb[d]), acc[d]);
        }
    }
    #pragma unroll
    for (int d = 0; d < 8; ++d) {
        acc[d] += __shfl_xor(acc[d], 8, 64);
        acc[d] += __shfl_xor(acc[d], 16, 64);
        acc[d] += __shfl_xor(acc[d], 32, 64);
    }
    if (g == 0) {
        float ba = 0.16f * alphaArr[c];          // beta = 4*MU/P * alpha
        const float4 h0 = *(const float4*)(h + (size_t)c * HIDC + k * 8);
        const float4 h1 = *(const float4*)(h + (size_t)c * HIDC + k * 8 + 4);
        float ov[8];
        ov[0] = fmaf(ba, h0.x, acc[0]); ov[1] = fmaf(ba, h0.y, acc[1]);
        ov[2] = fmaf(ba, h0.z, acc[2]); ov[3] = fmaf(ba, h0.w, acc[3]);
        ov[4] = fmaf(ba, h1.x, acc[4]); ov[5] = fmaf(ba, h1.y, acc[5]);
        ov[6] = fmaf(ba, h1.z, acc[6]); ov[7] = fmaf(ba, h1.w, acc[7]);
        if (outNext) {
            float4 o0 = make_float4(ov[0], ov[1], ov[2], ov[3]);
            float4 o1 = make_float4(ov[4], ov[5], ov[6], ov[7]);
            *(float4*)(outNext + (size_t)c * HIDC + k * 8) = o0;
            *(float4*)(outNext + (size_t)c * HIDC + k * 8 + 4) = o1;
        }
        if (soutNext) {
            ushort8 sv;
            #pragma unroll
            for (int d = 0; d < 8; ++d) sv[d] = f2bf(ov[d] * dc);
            *(ushort8*)(soutNext + (size_t)c * HIDC + k * 8) = sv;
        }
    }
}

// ---------------- head: log_softmax(out @ W2 + b2) via MFMA ----------------
__global__ __launch_bounds__(256, 4)
void k_head(const float* __restrict__ out, const float* __restrict__ W2,
            const float* __restrict__ b2, float* __restrict__ y,
            int N, int OUT) {
    __shared__ __align__(16) u16 wtH[48 * W2P];   // 6.75 KB
    __shared__ __align__(16) u16 wtL[48 * W2P];   // 6.75 KB
    const int tid = threadIdx.x;
    const int w = tid >> 6;
    const int l = tid & 63;
    const int q = l >> 4;
    const int i = l & 15;

    // stage W2^T (48 padded cols x 64 k) as bf16 hi/lo
    for (int idx = tid; idx < 48 * 64; idx += 256) {
        int n = idx >> 6, k = idx & 63;
        float v = (n < OUT) ? W2[k * OUT + n] : 0.0f;
        u16 hh = f2bf(v);
        wtH[n * W2P + k] = hh;
        wtL[n * W2P + k] = f2bf(v - bf2f(hh));
    }
    __syncthreads();

    int aRow = blockIdx.x * 64 + w * 16 + i;
    if (aRow > N - 1) aRow = N - 1;
    const float* op = out + (size_t)aRow * HIDC + q * 8;

    f32x4 acc[3];
    #pragma unroll
    for (int nt = 0; nt < 3; ++nt) acc[nt] = f32x4{0.f, 0.f, 0.f, 0.f};

    #pragma unroll
    for (int kst = 0; kst < 2; ++kst) {
        float4 c0 = *(const float4*)(op + kst * 32);
        float4 c1 = *(const float4*)(op + kst * 32 + 4);
        short8 ah, al;
        {
            float cf[8] = {c0.x, c0.y, c0.z, c0.w, c1.x, c1.y, c1.z, c1.w};
            #pragma unroll
            for (int j = 0; j < 8; ++j) {
                u16 hh = f2bf(cf[j]);
                ah[j] = (short)hh;
                al[j] = (short)f2bf(cf[j] - bf2f(hh));
            }
        }
        const int kl = kst * 32 + q * 8;
        #pragma unroll
        for (int nt = 0; nt < 3; ++nt) {
            const int boff = (nt * 16 + i) * W2P + kl;
            short8 bh = *(const short8*)(&wtH[boff]);
            short8 bl = *(const short8*)(&wtL[boff]);
            acc[nt] = __builtin_amdgcn_mfma_f32_16x16x32_bf16(ah, bh, acc[nt], 0, 0, 0);
            acc[nt] = __builtin_amdgcn_mfma_f32_16x16x32_bf16(al, bh, acc[nt], 0, 0, 0);
            acc[nt] = __builtin_amdgcn_mfma_f32_16x16x32_bf16(ah, bl, acc[nt], 0, 0, 0);
        }
    }

    float bv[3];
    #pragma unroll
    for (int nt = 0; nt < 3; ++nt) {
        int n = nt * 16 + i;
        bv[nt] = (n < OUT) ? b2[n] : 0.0f;
    }
    const int rowBaseW = blockIdx.x * 64 + w * 16 + q * 4;
    #pragma unroll
    for (int r = 0; r < 4; ++r) {
        int m = rowBaseW + r;
        float lg[3];
        #pragma unroll
        for (int nt = 0; nt < 3; ++nt) lg[nt] = acc[nt][r] + bv[nt];
        bool v2 = (32 + i) < OUT;                 // nt=2 validity (nt 0,1 always valid)
        float mx = fmaxf(lg[0], lg[1]);
        if (v2) mx = fmaxf(mx, lg[2]);
        #pragma unroll
        for (int sh = 1; sh < 16; sh <<= 1) mx = fmaxf(mx, __shfl_xor(mx, sh, 64));
        float e0 = __expf(lg[0] - mx);
        float e1 = __expf(lg[1] - mx);
        float e2 = v2 ? __expf(lg[2] - mx) : 0.0f;
        float s = e0 + e1 + e2;
        #pragma unroll
        for (int sh = 1; sh < 16; sh <<= 1) s += __shfl_xor(s, sh, 64);
        float ls = mx + __logf(s);
        if (m < N) {
            y[(size_t)m * OUT + i]      = lg[0] - ls;
            y[(size_t)m * OUT + 16 + i] = lg[1] - ls;
            if (v2) y[(size_t)m * OUT + 32 + i] = lg[2] - ls;
        }
    }
}

extern "C" void kernel_launch(void* const* d_in, const int* in_sizes, int n_in,
                              void* d_out, int out_size, void* d_ws, size_t ws_size,
                              hipStream_t stream) {
    const float* x  = (const float*)d_in[0];
    const int*   ei = (const int*)d_in[1];
    const float* W1 = (const float*)d_in[2];
    const float* b1 = (const float*)d_in[3];
    const float* W2 = (const float*)d_in[4];
    const float* b2 = (const float*)d_in[5];
    float* y = (float*)d_out;

    const int HID = in_sizes[3];            // 64
    const int IN  = in_sizes[2] / HID;      // 256
    const int OUT = in_sizes[5];            // 40
    const int N   = in_sizes[0] / IN;       // 100000
    const int E   = in_sizes[1] / 2;        // 1.6M
    const int* rowI = ei;
    const int* colI = ei + E;

    // workspace carve-up (float-granular; all counts even => 8B alignment holds)
    float* p = (float*)d_ws;
    float* dis   = p;  p += N;
    float* alpha = p;  p += N;
    float* Mcsr  = p;  p += E;
    float* h     = p;  p += (size_t)N * HID;     // raw MLP out (beta term)
    float* out2  = p;  p += (size_t)N * HID;     // final propagate output (f32)
    u16*   sh_bf = (u16*)p;  p += (size_t)N * HID / 2;   // bf16 dis*h
    u16*   sA_bf = (u16*)p;  p += (size_t)N * HID / 2;   // bf16 dis*out1
    int*   deg     = (int*)p;  p += N;
    int*   off     = (int*)p;  p += N;
    int*   cursor  = (int*)p;  p += N;
    int*   csr_src = (int*)p;  p += E;
    int*   bsum    = (int*)p;  p += (N + 255) / 256;

    const int TPB = 256;
    const int edgeBlocks = (E + TPB - 1) / TPB;
    const int nodeBlocks = (N + TPB - 1) / TPB;
    const int nodeWaveBlocks = (N + 3) / 4;    // 4 waves/block, wave per node
    const int regDiv = (N + 7) / 8;

    // CSR build: deg -> exclusive scan -> region-grouped fill
    hipMemsetAsync(deg, 0, sizeof(int) * N, stream);
    k_deg<<<edgeBlocks, TPB, 0, stream>>>(colI, deg, E);
    k_scanA<<<nodeBlocks, TPB, 0, stream>>>(deg, bsum, N);
    k_scanB<<<1, TPB, 0, stream>>>(bsum, nodeBlocks);
    k_scanC<<<nodeBlocks, TPB, 0, stream>>>(deg, bsum, dis, off, cursor, N);
    {
        int nch = (E + FILL_CH - 1) / FILL_CH;
        k_fill2<<<8 * nch, TPB, 0, stream>>>(rowI, colI, cursor, csr_src, E, regDiv);
    }

    // front MLP via MFMA (writes h f32 and sh_bf = bf16(dis*h)); 64 rows/block
    k_mlp1<<<(N + 63) / 64, TPB, 0, stream>>>(x, W1, b1, dis, h, sh_bf, N);

    // iteration 1: scur = sh_bf -> writes only sA_bf (raw out1 never consumed)
    k_calcM<<<nodeWaveBlocks, TPB, 0, stream>>>(csr_src, off, deg, dis, sh_bf, Mcsr, alpha, N);
    k_gather<<<nodeWaveBlocks, TPB, 0, stream>>>(csr_src, off, deg, dis, alpha, Mcsr,
                                                 sh_bf, h, (float*)nullptr, sA_bf, N);

    // iteration 2: scur = sA_bf -> writes raw out2 (f32)
    k_calcM<<<nodeWaveBlocks, TPB, 0, stream>>>(csr_src, off, deg, dis, sA_bf, Mcsr, alpha, N);
    k_gather<<<nodeWaveBlocks, TPB, 0, stream>>>(csr_src, off, deg, dis, alpha, Mcsr,
                                                 sA_bf, h, out2, (u16*)nullptr, N);

    // output head via MFMA; 64 rows/block
    k_head<<<(N + 63) / 64, TPB, 0, stream>>>(out2, W2, b2, y, N, OUT);
}